// Round 3
// baseline (379.584 us; speedup 1.0000x reference)
//
#include <hip/hip_runtime.h>
#include <cstdint>

// Problem dims
#define Bdim 8192   // batch
#define Hdim 1024   // hidden units (per gate)
#define Kdim 2048   // IN + H
// Tile dims (m97-proven 128x128 structure)
#define BM 128      // rows per block
#define BU 32       // units per block (x4 gates = 128 effective N)
#define BK 32       // K slab

#define XELEMS ((size_t)Bdim * Kdim)        // 16,777,216
#define WELEMS ((size_t)4 * Hdim * Kdim)    //  8,388,608
#define WGATE  ((size_t)Hdim * Kdim)        //  2,097,152

typedef __bf16 bf16;
typedef bf16  bf16x8  __attribute__((ext_vector_type(8)));
typedef float floatx4 __attribute__((ext_vector_type(4)));

typedef __attribute__((address_space(1))) uint32_t gu32;
typedef __attribute__((address_space(3))) uint32_t lu32;

__device__ __forceinline__ void gl_lds16(const bf16* g, bf16* l) {
    // async global->LDS, 16B/lane; LDS dest = wave-uniform base + lane*16
    __builtin_amdgcn_global_load_lds((gu32*)(bf16*)g, (lu32*)l, 16, 0, 0);
}

__device__ __forceinline__ float sigf(float x) {
    return 1.0f / (1.0f + __expf(-x));
}
__device__ __forceinline__ float tanhfast(float x) {
    return 2.0f / (1.0f + __expf(-2.0f * x)) - 1.0f;
}

// ---------------- fp32 -> bf16 conversion pre-pass ----------------
// Builds xc[B][K] = [hidden | inputs] (bf16) and wc[4][H][K] (bf16) in ws.
__global__ __launch_bounds__(256) void cvt_kernel(
    const float* __restrict__ inp, const float* __restrict__ hid,
    const float* __restrict__ Wf,  const float* __restrict__ Wi,
    const float* __restrict__ Wo,  const float* __restrict__ Wc,
    bf16* __restrict__ xc, bf16* __restrict__ wc)
{
    const size_t id = (size_t)blockIdx.x * 256 + threadIdx.x;  // 8-elem chunk
    const size_t e  = id * 8;
    const float* src;
    bf16* dst;
    if (e < XELEMS) {
        const size_t b = e >> 11;          // row (K=2048)
        const size_t k = e & (Kdim - 1);
        src = (k < Hdim) ? (hid + b * Hdim + k) : (inp + b * Hdim + (k - Hdim));
        dst = xc + e;
    } else {
        const size_t w = e - XELEMS;
        const size_t g = w >> 21;          // 2^21 == H*K
        const float* Ws = (g == 0) ? Wf : (g == 1) ? Wi : (g == 2) ? Wo : Wc;
        src = Ws + (w & (WGATE - 1));
        dst = wc + w;
    }
    const float4 a  = *reinterpret_cast<const float4*>(src);
    const float4 b4 = *reinterpret_cast<const float4*>(src + 4);
    bf16x8 o;
    o[0] = (bf16)a.x;  o[1] = (bf16)a.y;  o[2] = (bf16)a.z;  o[3] = (bf16)a.w;
    o[4] = (bf16)b4.x; o[5] = (bf16)b4.y; o[6] = (bf16)b4.z; o[7] = (bf16)b4.w;
    *reinterpret_cast<bf16x8*>(dst) = o;
}

// ---------------- fused LSTM GEMM + epilogue ----------------
__global__ __launch_bounds__(256) void lstm_fused(
    const bf16* __restrict__ xc,   const bf16* __restrict__ wc,
    const float* __restrict__ cin,
    const float* __restrict__ bfv, const float* __restrict__ biv,
    const float* __restrict__ bov, const float* __restrict__ bcv,
    float* __restrict__ out)
{
    __shared__ __align__(16) bf16 As[BM * BK];    // [row][k], 64B rows
    __shared__ __align__(16) bf16 Bs[128 * BK];   // [n = g*32 + ul][k]

    const int tid  = threadIdx.x;
    const int lane = tid & 63;
    const int wv   = tid >> 6;      // wave 0..3 -> row group
    const int quad = lane >> 4;
    const int l16  = lane & 15;

    const int m0 = blockIdx.x * BM;
    const int u0 = blockIdx.y * BU;

    // staging: thread writes 16B chunk (tid&3) of LDS row (tid>>2)
    const int r0   = tid >> 2;          // [0,64)
    const int koff = (tid & 3) * 8;     // bf16 elems within BK slab

    const bf16* xA0 = xc + (size_t)(m0 + r0) * Kdim + koff;
    const bf16* xA1 = xA0 + (size_t)64 * Kdim;

    // B rows: n0 = r0 in [0,64) -> gates {f,i}; n1 = 64+r0 -> gates {o,c}
    const int ul = r0 & 31;
    const int ghalf = (tid & 128) ? 1 : 0;
    const bf16* WB0 = wc + (size_t)(ghalf)     * WGATE + (size_t)(u0 + ul) * Kdim + koff;
    const bf16* WB1 = wc + (size_t)(ghalf + 2) * WGATE + (size_t)(u0 + ul) * Kdim + koff;

    bf16* lA0 = &As[tid * 8];
    bf16* lA1 = &As[(256 + tid) * 8];
    bf16* lB0 = &Bs[tid * 8];
    bf16* lB1 = &Bs[(256 + tid) * 8];

    floatx4 acc[2][2][4] = {};  // [row-half a][unit-half h][gate g]

    for (int k0 = 0; k0 < Kdim; k0 += BK) {
        gl_lds16(xA0 + k0, lA0);
        gl_lds16(xA1 + k0, lA1);
        gl_lds16(WB0 + k0, lB0);
        gl_lds16(WB1 + k0, lB1);
        __syncthreads();

        bf16x8 af[2];
        af[0] = *reinterpret_cast<const bf16x8*>(&As[(wv * 32 +      l16) * BK + quad * 8]);
        af[1] = *reinterpret_cast<const bf16x8*>(&As[(wv * 32 + 16 + l16) * BK + quad * 8]);
        bf16x8 bfr[2][4];
        #pragma unroll
        for (int h = 0; h < 2; ++h)
            #pragma unroll
            for (int g = 0; g < 4; ++g)
                bfr[h][g] = *reinterpret_cast<const bf16x8*>(
                    &Bs[(g * 32 + h * 16 + l16) * BK + quad * 8]);

        #pragma unroll
        for (int a = 0; a < 2; ++a)
            #pragma unroll
            for (int h = 0; h < 2; ++h)
                #pragma unroll
                for (int g = 0; g < 4; ++g)
                    acc[a][h][g] = __builtin_amdgcn_mfma_f32_16x16x32_bf16(
                        af[a], bfr[h][g], acc[a][h][g], 0, 0, 0);
        __syncthreads();
    }

    // fused LSTM epilogue: all 4 gates of (row,unit) live in this lane
    const int row_base = m0 + wv * 32 + quad * 4;
    #pragma unroll
    for (int h = 0; h < 2; ++h) {
        const int unit = u0 + h * 16 + l16;
        const float bff = bfv[unit];
        const float bii = biv[unit];
        const float boo = bov[unit];
        const float bcc = bcv[unit];
        #pragma unroll
        for (int a = 0; a < 2; ++a) {
            #pragma unroll
            for (int r = 0; r < 4; ++r) {
                const int row = row_base + a * 16 + r;
                const size_t off = (size_t)row * Hdim + unit;
                const float fg = sigf(acc[a][h][0][r] + bff);
                const float ig = sigf(acc[a][h][1][r] + bii);
                const float og = sigf(acc[a][h][2][r] + boo);
                const float ch = tanhfast(acc[a][h][3][r] + bcc);
                const float cn = fg * cin[off] + ig * ch;
                const float hn = og * tanhfast(cn);
                out[off] = hn;                               // h_new (fp32)
                out[(size_t)Bdim * Hdim + off] = cn;         // c_new (fp32)
            }
        }
    }
}

extern "C" void kernel_launch(void* const* d_in, const int* in_sizes, int n_in,
                              void* d_out, int out_size, void* d_ws, size_t ws_size,
                              hipStream_t stream) {
    const float* inputs = (const float*)d_in[0];
    const float* hidden = (const float*)d_in[1];
    const float* cprev  = (const float*)d_in[2];
    const float* Wf     = (const float*)d_in[3];
    const float* bfp    = (const float*)d_in[4];
    const float* Wi     = (const float*)d_in[5];
    const float* bip    = (const float*)d_in[6];
    const float* Wo     = (const float*)d_in[7];
    const float* bop    = (const float*)d_in[8];
    const float* Wc     = (const float*)d_in[9];
    const float* bcp    = (const float*)d_in[10];
    float* out = (float*)d_out;

    // ws layout: xc (32 MB) | wc (16 MB)
    const size_t need = (XELEMS + WELEMS) * sizeof(bf16);
    if (ws_size < need) return;  // insufficient scratch -> wrong answer, not a fault
    bf16* xc = (bf16*)d_ws;
    bf16* wc = xc + XELEMS;

    const int cvt_blocks = (int)((XELEMS + WELEMS) / 8 / 256);  // 12288
    cvt_kernel<<<dim3(cvt_blocks), dim3(256), 0, stream>>>(
        inputs, hidden, Wf, Wi, Wo, Wc, xc, wc);

    dim3 grid(Bdim / BM, Hdim / BU);   // 64 x 32 = 2048 blocks
    lstm_fused<<<grid, dim3(256), 0, stream>>>(
        xc, wc, cprev, bfp, bip, bop, bcp, out);
}

// Round 4
// 341.489 us; speedup vs baseline: 1.1116x; 1.1116x over previous
//
#include <hip/hip_runtime.h>
#include <cstdint>

// Problem dims
#define Bdim 8192   // batch
#define Hdim 1024   // hidden units (per gate)
#define Kdim 2048   // IN + H
// Tile dims
#define BM 128      // rows per block
#define BU 64       // units per block (x4 gates = 256 effective N)
#define BK 32       // K slab

#define XELEMS ((size_t)Bdim * Kdim)        // 16,777,216
#define WELEMS ((size_t)4 * Hdim * Kdim)    //  8,388,608
#define WGATE  ((size_t)Hdim * Kdim)        //  2,097,152

typedef __bf16 bf16;
typedef bf16  bf16x8  __attribute__((ext_vector_type(8)));
typedef float floatx4 __attribute__((ext_vector_type(4)));

typedef __attribute__((address_space(1))) uint32_t gu32;
typedef __attribute__((address_space(3))) uint32_t lu32;

__device__ __forceinline__ void gl_lds16(const bf16* g, bf16* l) {
    // async global->LDS, 16B/lane; LDS dest = wave-uniform base + lane*16
    __builtin_amdgcn_global_load_lds((gu32*)(bf16*)g, (lu32*)l, 16, 0, 0);
}

__device__ __forceinline__ float sigf(float x) {
    return 1.0f / (1.0f + __expf(-x));
}
__device__ __forceinline__ float tanhfast(float x) {
    return 2.0f / (1.0f + __expf(-2.0f * x)) - 1.0f;
}

// ---------------- fp32 -> bf16 conversion pre-pass ----------------
__global__ __launch_bounds__(256) void cvt_kernel(
    const float* __restrict__ inp, const float* __restrict__ hid,
    const float* __restrict__ Wf,  const float* __restrict__ Wi,
    const float* __restrict__ Wo,  const float* __restrict__ Wc,
    bf16* __restrict__ xc, bf16* __restrict__ wc)
{
    const size_t id = (size_t)blockIdx.x * 256 + threadIdx.x;  // 8-elem chunk
    const size_t e  = id * 8;
    const float* src;
    bf16* dst;
    if (e < XELEMS) {
        const size_t b = e >> 11;          // row (K=2048)
        const size_t k = e & (Kdim - 1);
        src = (k < Hdim) ? (hid + b * Hdim + k) : (inp + b * Hdim + (k - Hdim));
        dst = xc + e;
    } else {
        const size_t w = e - XELEMS;
        const size_t g = w >> 21;          // 2^21 == H*K
        const float* Ws = (g == 0) ? Wf : (g == 1) ? Wi : (g == 2) ? Wo : Wc;
        src = Ws + (w & (WGATE - 1));
        dst = wc + w;
    }
    const float4 a  = *reinterpret_cast<const float4*>(src);
    const float4 b4 = *reinterpret_cast<const float4*>(src + 4);
    bf16x8 o;
    o[0] = (bf16)a.x;  o[1] = (bf16)a.y;  o[2] = (bf16)a.z;  o[3] = (bf16)a.w;
    o[4] = (bf16)b4.x; o[5] = (bf16)b4.y; o[6] = (bf16)b4.z; o[7] = (bf16)b4.w;
    *reinterpret_cast<bf16x8*>(dst) = o;
}

// ---------------- fused LSTM GEMM + epilogue ----------------
// Wave tile: 64 rows x (4 gates x 32 units) = 4 A-frags x 8 B-frags = 32 MFMA
// per K-iter for 12 ds_read_b128 (0.375 reads/MFMA).
// LDS k-chunk XOR swizzle: global chunk q of row r lives at slot q^((r>>1)&3)
// -> frag reads hit 8 distinct banks x 2 lanes (2-way aliasing = free).
__global__ __launch_bounds__(256, 2) void lstm_fused(
    const bf16* __restrict__ xc,   const bf16* __restrict__ wc,
    const float* __restrict__ cin,
    const float* __restrict__ bfv, const float* __restrict__ biv,
    const float* __restrict__ bov, const float* __restrict__ bcv,
    float* __restrict__ out)
{
    __shared__ __align__(16) bf16 As[BM * BK];        // 8 KB  [row][slot]
    __shared__ __align__(16) bf16 Bs[4 * BU * BK];    // 16 KB [g*64+u][slot]

    const int tid  = threadIdx.x;
    const int lane = tid & 63;
    const int wv   = tid >> 6;
    const int quad = lane >> 4;
    const int l16  = lane & 15;

    const int m0 = blockIdx.x * BM;
    const int u0 = blockIdx.y * BU;

    // ---- staging setup (source-side swizzle; LDS dest fixed at li*16B) ----
    // A: 2 calls, li = c*256 + tid; row = li>>2 in [0,128); slot = li&3
    const bf16* gA[2];
    bf16* lA[2];
    #pragma unroll
    for (int c = 0; c < 2; ++c) {
        const int li   = c * 256 + tid;
        const int row  = li >> 2;
        const int slot = li & 3;
        const int gch  = slot ^ ((row >> 1) & 3);
        gA[c] = xc + (size_t)(m0 + row) * Kdim + gch * 8;
        lA[c] = &As[li * 8];
    }
    // B: 4 calls, nr = li>>2 in [0,256); gate = nr>>6, unit = nr&63
    const bf16* gB[4];
    bf16* lB[4];
    #pragma unroll
    for (int c = 0; c < 4; ++c) {
        const int li   = c * 256 + tid;
        const int nr   = li >> 2;
        const int slot = li & 3;
        const int gch  = slot ^ ((nr >> 1) & 3);
        const int g    = nr >> 6;
        const int ul   = nr & 63;
        gB[c] = wc + (size_t)g * WGATE + (size_t)(u0 + ul) * Kdim + gch * 8;
        lB[c] = &Bs[li * 8];
    }

    // ---- fragment read addressing (slot uniform per lane) ----
    const int kslot = quad ^ ((l16 >> 1) & 3);          // swizzled k-chunk slot
    const int rbase = (wv & 1) * 64;                    // wave's row half
    const int ubase = (wv >> 1) * 32;                   // wave's unit half

    floatx4 acc[4][2][4] = {};  // [a: row-frag][h: unit-16][g: gate]

    for (int k0 = 0; k0 < Kdim; k0 += BK) {
        gl_lds16(gA[0] + k0, lA[0]);
        gl_lds16(gA[1] + k0, lA[1]);
        gl_lds16(gB[0] + k0, lB[0]);
        gl_lds16(gB[1] + k0, lB[1]);
        gl_lds16(gB[2] + k0, lB[2]);
        gl_lds16(gB[3] + k0, lB[3]);
        __syncthreads();

        bf16x8 af[4];
        #pragma unroll
        for (int a = 0; a < 4; ++a)
            af[a] = *reinterpret_cast<const bf16x8*>(
                &As[(rbase + a * 16 + l16) * BK + kslot * 8]);
        bf16x8 bfr[2][4];
        #pragma unroll
        for (int h = 0; h < 2; ++h)
            #pragma unroll
            for (int g = 0; g < 4; ++g)
                bfr[h][g] = *reinterpret_cast<const bf16x8*>(
                    &Bs[(g * 64 + ubase + h * 16 + l16) * BK + kslot * 8]);

        #pragma unroll
        for (int a = 0; a < 4; ++a)
            #pragma unroll
            for (int h = 0; h < 2; ++h)
                #pragma unroll
                for (int g = 0; g < 4; ++g)
                    acc[a][h][g] = __builtin_amdgcn_mfma_f32_16x16x32_bf16(
                        af[a], bfr[h][g], acc[a][h][g], 0, 0, 0);
        __syncthreads();
    }

    // ---- fused LSTM epilogue ----
    const int m_base = m0 + rbase + quad * 4;
    const int u_base = u0 + ubase;
    #pragma unroll
    for (int h = 0; h < 2; ++h) {
        const int unit = u_base + h * 16 + l16;
        const float bff = bfv[unit];
        const float bii = biv[unit];
        const float boo = bov[unit];
        const float bcc = bcv[unit];
        #pragma unroll
        for (int a = 0; a < 4; ++a) {
            #pragma unroll
            for (int r = 0; r < 4; ++r) {
                const int row = m_base + a * 16 + r;
                const size_t off = (size_t)row * Hdim + unit;
                const float fg = sigf(acc[a][h][0][r] + bff);
                const float ig = sigf(acc[a][h][1][r] + bii);
                const float og = sigf(acc[a][h][2][r] + boo);
                const float ch = tanhfast(acc[a][h][3][r] + bcc);
                const float cn = fg * cin[off] + ig * ch;
                const float hn = og * tanhfast(cn);
                out[off] = hn;                         // h_new
                out[(size_t)Bdim * Hdim + off] = cn;   // c_new
            }
        }
    }
}

extern "C" void kernel_launch(void* const* d_in, const int* in_sizes, int n_in,
                              void* d_out, int out_size, void* d_ws, size_t ws_size,
                              hipStream_t stream) {
    const float* inputs = (const float*)d_in[0];
    const float* hidden = (const float*)d_in[1];
    const float* cprev  = (const float*)d_in[2];
    const float* Wf     = (const float*)d_in[3];
    const float* bfp    = (const float*)d_in[4];
    const float* Wi     = (const float*)d_in[5];
    const float* bip    = (const float*)d_in[6];
    const float* Wo     = (const float*)d_in[7];
    const float* bop    = (const float*)d_in[8];
    const float* Wc     = (const float*)d_in[9];
    const float* bcp    = (const float*)d_in[10];
    float* out = (float*)d_out;

    const size_t need = (XELEMS + WELEMS) * sizeof(bf16);
    if (ws_size < need) return;
    bf16* xc = (bf16*)d_ws;
    bf16* wc = xc + XELEMS;

    const int cvt_blocks = (int)((XELEMS + WELEMS) / 8 / 256);  // 12288
    cvt_kernel<<<dim3(cvt_blocks), dim3(256), 0, stream>>>(
        inputs, hidden, Wf, Wi, Wo, Wc, xc, wc);

    dim3 grid(Bdim / BM, Hdim / BU);   // 64 x 16 = 1024 blocks
    lstm_fused<<<grid, dim3(256), 0, stream>>>(
        xc, wc, cprev, bfp, bip, bop, bcp, out);
}

// Round 5
// 334.543 us; speedup vs baseline: 1.1346x; 1.0208x over previous
//
#include <hip/hip_runtime.h>
#include <cstdint>

// Problem dims
#define Bdim 8192   // batch
#define Hdim 1024   // hidden units (per gate)
#define Kdim 2048   // IN + H
// Tile dims
#define BM 128      // rows per block
#define BU 64       // units per block (x4 gates = 256 effective N)
// K loop: 64 per iteration = two 32-k slabs, each in its own LDS buffer with
// the round-4-proven (measured 0-conflict) [row][4 chunks, XOR-swizzled] layout.

#define XELEMS ((size_t)Bdim * Kdim)        // 16,777,216
#define WELEMS ((size_t)4 * Hdim * Kdim)    //  8,388,608
#define WGATE  ((size_t)Hdim * Kdim)        //  2,097,152

typedef __bf16 bf16;
typedef bf16  bf16x8   __attribute__((ext_vector_type(8)));
typedef float floatx16 __attribute__((ext_vector_type(16)));

typedef __attribute__((address_space(1))) uint32_t gu32;
typedef __attribute__((address_space(3))) uint32_t lu32;

__device__ __forceinline__ void gl_lds16(const bf16* g, bf16* l) {
    __builtin_amdgcn_global_load_lds((gu32*)(bf16*)g, (lu32*)l, 16, 0, 0);
}

__device__ __forceinline__ float sigf(float x) {
    return 1.0f / (1.0f + __expf(-x));
}
__device__ __forceinline__ float tanhfast(float x) {
    return 2.0f / (1.0f + __expf(-2.0f * x)) - 1.0f;
}

// ---------------- fp32 -> bf16 conversion pre-pass ----------------
__global__ __launch_bounds__(256) void cvt_kernel(
    const float* __restrict__ inp, const float* __restrict__ hid,
    const float* __restrict__ Wf,  const float* __restrict__ Wi,
    const float* __restrict__ Wo,  const float* __restrict__ Wc,
    bf16* __restrict__ xc, bf16* __restrict__ wc)
{
    const size_t id = (size_t)blockIdx.x * 256 + threadIdx.x;  // 8-elem chunk
    const size_t e  = id * 8;
    const float* src;
    bf16* dst;
    if (e < XELEMS) {
        const size_t b = e >> 11;          // row (K=2048)
        const size_t k = e & (Kdim - 1);
        src = (k < Hdim) ? (hid + b * Hdim + k) : (inp + b * Hdim + (k - Hdim));
        dst = xc + e;
    } else {
        const size_t w = e - XELEMS;
        const size_t g = w >> 21;          // 2^21 == H*K
        const float* Ws = (g == 0) ? Wf : (g == 1) ? Wi : (g == 2) ? Wo : Wc;
        src = Ws + (w & (WGATE - 1));
        dst = wc + w;
    }
    const float4 a  = *reinterpret_cast<const float4*>(src);
    const float4 b4 = *reinterpret_cast<const float4*>(src + 4);
    bf16x8 o;
    o[0] = (bf16)a.x;  o[1] = (bf16)a.y;  o[2] = (bf16)a.z;  o[3] = (bf16)a.w;
    o[4] = (bf16)b4.x; o[5] = (bf16)b4.y; o[6] = (bf16)b4.z; o[7] = (bf16)b4.w;
    *reinterpret_cast<bf16x8*>(dst) = o;
}

// ---------------- fused LSTM GEMM + epilogue ----------------
// 32x32x16 MFMA. Wave tile: 64 rows x 32 units x 4 gates.
// Per 32-k slab per wave: 4 A + 8 B ds_read_b128, 16 MFMA (32768 FLOP each).
// A-operand layout: A[m = lane&31][k = (lane>>5)*8 + j]  (B symmetric).
// C/D layout (m74/m101): col = lane&31, row = (reg&3) + 8*(reg>>2) + 4*(lane>>5).
__global__ __launch_bounds__(256, 2) void lstm_fused(
    const bf16* __restrict__ xc,   const bf16* __restrict__ wc,
    const float* __restrict__ cin,
    const float* __restrict__ bfv, const float* __restrict__ biv,
    const float* __restrict__ bov, const float* __restrict__ bcv,
    float* __restrict__ out)
{
    // [slab][row][32k as 4 chunks of 8, chunk stored at slot chunk^((row>>1)&3)]
    __shared__ __align__(16) bf16 As[2 * BM * 32];        // 16 KB
    __shared__ __align__(16) bf16 Bs[2 * 4 * BU * 32];    // 32 KB

    const int tid  = threadIdx.x;
    const int lane = tid & 63;
    const int wv   = tid >> 6;
    const int m31  = lane & 31;
    const int h32  = lane >> 5;

    const int m0 = blockIdx.x * BM;
    const int u0 = blockIdx.y * BU;

    // ---- staging setup (source-side swizzle; LDS dest = base + lane*16) ----
    const bf16* gA[2];      // A: rows (li>>2), chunk slot li&3
    bf16* lA[2];
    #pragma unroll
    for (int c = 0; c < 2; ++c) {
        const int li   = c * 256 + tid;
        const int row  = li >> 2;
        const int slot = li & 3;
        const int gch  = slot ^ ((row >> 1) & 3);
        gA[c] = xc + (size_t)(m0 + row) * Kdim + gch * 8;
        lA[c] = &As[li * 8];
    }
    const bf16* gB[4];      // B: n-rows (g*64+u)
    bf16* lB[4];
    #pragma unroll
    for (int c = 0; c < 4; ++c) {
        const int li   = c * 256 + tid;
        const int nr   = li >> 2;
        const int slot = li & 3;
        const int gch  = slot ^ ((nr >> 1) & 3);
        const int g    = nr >> 6;
        const int ul   = nr & 63;
        gB[c] = wc + (size_t)g * WGATE + (size_t)(u0 + ul) * Kdim + gch * 8;
        lB[c] = &Bs[li * 8];
    }

    // ---- fragment read offsets (elements) ----
    const int rbase = (wv & 1) * 64;    // wave's 64-row half
    const int ubase = (wv >> 1) * 32;   // wave's 32-unit half
    int aoff[2][2];                     // [a: row frag][ks: k-half]
    #pragma unroll
    for (int a = 0; a < 2; ++a) {
        const int ra = rbase + a * 32 + m31;
        const int t  = (ra >> 1) & 3;
        #pragma unroll
        for (int ks = 0; ks < 2; ++ks)
            aoff[a][ks] = ra * 32 + (((ks * 2 + h32) ^ t) * 8);
    }
    int boff[4][2];                     // [g: gate][ks]
    #pragma unroll
    for (int g = 0; g < 4; ++g) {
        const int rb = g * 64 + ubase + m31;
        const int t  = (rb >> 1) & 3;
        #pragma unroll
        for (int ks = 0; ks < 2; ++ks)
            boff[g][ks] = rb * 32 + (((ks * 2 + h32) ^ t) * 8);
    }

    floatx16 acc[2][4] = {};            // [a: row frag][g: gate]

    for (int k0 = 0; k0 < Kdim; k0 += 64) {
        // stage both 32-k slabs, then one barrier
        #pragma unroll
        for (int s = 0; s < 2; ++s) {
            const int kk = k0 + s * 32;
            gl_lds16(gA[0] + kk, lA[0] + s * (BM * 32));
            gl_lds16(gA[1] + kk, lA[1] + s * (BM * 32));
            gl_lds16(gB[0] + kk, lB[0] + s * (4 * BU * 32));
            gl_lds16(gB[1] + kk, lB[1] + s * (4 * BU * 32));
            gl_lds16(gB[2] + kk, lB[2] + s * (4 * BU * 32));
            gl_lds16(gB[3] + kk, lB[3] + s * (4 * BU * 32));
        }
        __syncthreads();

        #pragma unroll
        for (int s = 0; s < 2; ++s) {
            const bf16* Ab = As + s * (BM * 32);
            const bf16* Bb = Bs + s * (4 * BU * 32);
            bf16x8 af[2][2];
            #pragma unroll
            for (int a = 0; a < 2; ++a)
                #pragma unroll
                for (int ks = 0; ks < 2; ++ks)
                    af[a][ks] = *reinterpret_cast<const bf16x8*>(Ab + aoff[a][ks]);
            bf16x8 bg[4][2];
            #pragma unroll
            for (int g = 0; g < 4; ++g)
                #pragma unroll
                for (int ks = 0; ks < 2; ++ks)
                    bg[g][ks] = *reinterpret_cast<const bf16x8*>(Bb + boff[g][ks]);

            #pragma unroll
            for (int ks = 0; ks < 2; ++ks)
                #pragma unroll
                for (int a = 0; a < 2; ++a)
                    #pragma unroll
                    for (int g = 0; g < 4; ++g)
                        acc[a][g] = __builtin_amdgcn_mfma_f32_32x32x16_bf16(
                            af[a][ks], bg[g][ks], acc[a][g], 0, 0, 0);
        }
        __syncthreads();
    }

    // ---- fused LSTM epilogue (one unit per lane) ----
    const int m_base = m0 + rbase + 4 * h32;
    const int unit   = u0 + ubase + m31;
    const float bff = bfv[unit];
    const float bii = biv[unit];
    const float boo = bov[unit];
    const float bcc = bcv[unit];
    #pragma unroll
    for (int a = 0; a < 2; ++a) {
        #pragma unroll
        for (int rg = 0; rg < 16; ++rg) {
            const int row = m_base + a * 32 + (rg & 3) + 8 * (rg >> 2);
            const size_t off = (size_t)row * Hdim + unit;
            const float fg = sigf(acc[a][0][rg] + bff);
            const float ig = sigf(acc[a][1][rg] + bii);
            const float og = sigf(acc[a][2][rg] + boo);
            const float ch = tanhfast(acc[a][3][rg] + bcc);
            const float cn = fg * cin[off] + ig * ch;
            const float hn = og * tanhfast(cn);
            out[off] = hn;                         // h_new
            out[(size_t)Bdim * Hdim + off] = cn;   // c_new
        }
    }
}

extern "C" void kernel_launch(void* const* d_in, const int* in_sizes, int n_in,
                              void* d_out, int out_size, void* d_ws, size_t ws_size,
                              hipStream_t stream) {
    const float* inputs = (const float*)d_in[0];
    const float* hidden = (const float*)d_in[1];
    const float* cprev  = (const float*)d_in[2];
    const float* Wf     = (const float*)d_in[3];
    const float* bfp    = (const float*)d_in[4];
    const float* Wi     = (const float*)d_in[5];
    const float* bip    = (const float*)d_in[6];
    const float* Wo     = (const float*)d_in[7];
    const float* bop    = (const float*)d_in[8];
    const float* Wc     = (const float*)d_in[9];
    const float* bcp    = (const float*)d_in[10];
    float* out = (float*)d_out;

    const size_t need = (XELEMS + WELEMS) * sizeof(bf16);
    if (ws_size < need) return;
    bf16* xc = (bf16*)d_ws;
    bf16* wc = xc + XELEMS;

    const int cvt_blocks = (int)((XELEMS + WELEMS) / 8 / 256);  // 12288
    cvt_kernel<<<dim3(cvt_blocks), dim3(256), 0, stream>>>(
        inputs, hidden, Wf, Wi, Wo, Wc, xc, wc);

    dim3 grid(Bdim / BM, Hdim / BU);   // 64 x 16 = 1024 blocks
    lstm_fused<<<grid, dim3(256), 0, stream>>>(
        xc, wc, cprev, bfp, bip, bop, bcp, out);
}